// Round 14
// baseline (178.151 us; speedup 1.0000x reference)
//
#include <hip/hip_runtime.h>

#define EPSF 1e-7f

constexpr int Bn = 4, Cn = 64, Kn = 19;
constexpr int HWn = 512 * 512;

// k_stats v6 (R14): 16KB-burst staged MFMA, stat-packed B operand.
// R13 lesson: BW scales with per-channel-row burst length (256B->1.8, 8KB->3.1,
// 16KB->~6.9 TB/s). Tile = [16ch x 4096px]; wave loads one full 16KB row.
// B cols 0-15 = x, cols 16-31 = x^2 (same channels) -> one MFMA yields S and Q.
constexpr int SCH   = 64;                  // stats chunks per image
constexpr int SPIX  = HWn / SCH;           // 4096 px per block
constexpr int SBLK  = 1024;                // 16 waves
constexpr int TSTR  = 4104;                // tile row stride (bf16): 16B-aligned rows, 2-way banks
constexpr int PARTSZ = 2464;               // 2432 stats + 19 counts + pad

typedef float f32x16_t __attribute__((ext_vector_type(16)));
typedef float f32x4_t  __attribute__((ext_vector_type(4)));
typedef short bf16x8_t __attribute__((ext_vector_type(8)));

#define PKBF(lo, hi) ((__builtin_bit_cast(unsigned, (hi)) & 0xFFFF0000u) | \
                      (__builtin_bit_cast(unsigned, (lo)) >> 16))

__global__ __launch_bounds__(SBLK, 4) void k_stats(
    const float* __restrict__ x, const int* __restrict__ gt,
    float* __restrict__ part)
{
    __shared__ unsigned short tile[16 * TSTR];   // 131,328 B (reused as reduce scratch)
    __shared__ int   lab[SPIX];                  // 16,384 B
    __shared__ float credL[32];

    const int tid  = threadIdx.x;
    const int lane = tid & 63;
    const int w    = tid >> 6;                   // wave 0..15
    const int g    = lane >> 5;                  // k-slot half
    const int col  = lane & 31;                  // A row (class) / D col (channel|stat)
    const int ch16 = col & 15;                   // B channel row within tile

    const int b    = blockIdx.x >> 6;
    const int pix0 = (blockIdx.x & 63) * SPIX;
    const float* xb  = x  + (size_t)b * Cn * HWn + pix0;
    const int*   gtb = gt + (size_t)b * HWn + pix0;

    // stage labels once (clamped)
    {
        const int4 v = *reinterpret_cast<const int4*>(gtb + tid * 4);
        int4 cl;
        cl.x = min(max(v.x, 0), Kn - 1); cl.y = min(max(v.y, 0), Kn - 1);
        cl.z = min(max(v.z, 0), Kn - 1); cl.w = min(max(v.w, 0), Kn - 1);
        *reinterpret_cast<int4*>(&lab[tid * 4]) = cl;
    }

    // 4 named round accumulators (rule #20: no runtime-indexed arrays)
    f32x16_t dR0 = (f32x16_t)0.f, dR1 = (f32x16_t)0.f;
    f32x16_t dR2 = (f32x16_t)0.f, dR3 = (f32x16_t)0.f;
    int cnt = 0;

    // stage round R: wave w loads channel R*16+w, FULL 4096 px = 16KB contiguous
#define STAGE_(R) { \
    const float* src = xb + (size_t)((R) * 16 + w) * HWn; \
    unsigned short* dst = &tile[w * TSTR]; \
    _Pragma("unroll") \
    for (int i = 0; i < 16; ++i) { \
        const float4 v = *reinterpret_cast<const float4*>(src + i * 256 + lane * 4); \
        uint2 pk; pk.x = PKBF(v.x, v.y); pk.y = PKBF(v.z, v.w); \
        *reinterpret_cast<uint2*>(&dst[i * 256 + lane * 4]) = pk; \
    } }

    // compute round R: wave w owns pixels [w*256, w*256+256), 16 MFMA steps.
    // B: cols<16 feed x, cols>=16 feed x^2 of channel ch16 (one MFMA -> S+Q).
    // A onehot unchanged from R11 (verified); C/D: col=lane&31,
    // row=(reg&3)+8*(reg>>2)+4*(lane>>5).
#define COMPUTE_(R, D, CNTON) { \
    _Pragma("unroll 1") \
    for (int s = 0; s < 16; ++s) { \
        const int pg = w * 256 + s * 16 + 8 * g; \
        uint4 bw = *reinterpret_cast<const uint4*>(&tile[ch16 * TSTR + pg]); \
        if (col >= 16) { \
            const float f0 = __builtin_bit_cast(float, bw.x << 16); \
            const float f1 = __builtin_bit_cast(float, bw.x & 0xFFFF0000u); \
            const float f2 = __builtin_bit_cast(float, bw.y << 16); \
            const float f3 = __builtin_bit_cast(float, bw.y & 0xFFFF0000u); \
            const float f4 = __builtin_bit_cast(float, bw.z << 16); \
            const float f5 = __builtin_bit_cast(float, bw.z & 0xFFFF0000u); \
            const float f6 = __builtin_bit_cast(float, bw.w << 16); \
            const float f7 = __builtin_bit_cast(float, bw.w & 0xFFFF0000u); \
            bw.x = PKBF(f0 * f0, f1 * f1); bw.y = PKBF(f2 * f2, f3 * f3); \
            bw.z = PKBF(f4 * f4, f5 * f5); bw.w = PKBF(f6 * f6, f7 * f7); \
        } \
        const int4 L0 = *reinterpret_cast<const int4*>(&lab[pg]); \
        const int4 L1 = *reinterpret_cast<const int4*>(&lab[pg + 4]); \
        const bool e0 = (L0.x == col), e1 = (L0.y == col); \
        const bool e2 = (L0.z == col), e3 = (L0.w == col); \
        const bool e4 = (L1.x == col), e5 = (L1.y == col); \
        const bool e6 = (L1.z == col), e7 = (L1.w == col); \
        int4 av; \
        av.x = (e0 ? 0x3F80u : 0u) | (e1 ? 0x3F800000u : 0u); \
        av.y = (e2 ? 0x3F80u : 0u) | (e3 ? 0x3F800000u : 0u); \
        av.z = (e4 ? 0x3F80u : 0u) | (e5 ? 0x3F800000u : 0u); \
        av.w = (e6 ? 0x3F80u : 0u) | (e7 ? 0x3F800000u : 0u); \
        if (CNTON) cnt += (int)e0 + (int)e1 + (int)e2 + (int)e3 \
                        + (int)e4 + (int)e5 + (int)e6 + (int)e7; \
        D = __builtin_amdgcn_mfma_f32_32x32x16_bf16( \
                __builtin_bit_cast(bf16x8_t, av), \
                __builtin_bit_cast(bf16x8_t, bw), D, 0, 0, 0); \
    } }

    __syncthreads();                 // labels staged
    STAGE_(0)
    __syncthreads();
    COMPUTE_(0, dR0, true)           // counts once: each round covers all 4096 px
    __syncthreads();
    STAGE_(1)
    __syncthreads();
    COMPUTE_(1, dR1, false)
    __syncthreads();
    STAGE_(2)
    __syncthreads();
    COMPUTE_(2, dR2, false)
    __syncthreads();
    STAGE_(3)
    __syncthreads();
    COMPUTE_(3, dR3, false)

    const int cnt2 = cnt + __shfl(cnt, col + 32, 64);

    // cross-wave reduce into tile-as-scratch: redf[k*128 + stat*64 + ch]
    __syncthreads();
    float* redf = reinterpret_cast<float*>(tile);
    const int statO = (col >> 4) * 64;           // 0 = S, 64 = Q
#define RED_(R, D, OP) { \
    _Pragma("unroll") \
    for (int r = 0; r < 16; ++r) { \
        const int krow = (r & 3) + 8 * (r >> 2) + 4 * g; \
        if (krow < Kn) redf[krow * 128 + statO + (R) * 16 + ch16] OP D[r]; \
    } }
    #pragma unroll 1
    for (int ww = 0; ww < 16; ++ww) {
        if (w == ww) {
            if (ww == 0) { RED_(0, dR0, =)  RED_(1, dR1, =)  RED_(2, dR2, =)  RED_(3, dR3, =) }
            else         { RED_(0, dR0, +=) RED_(1, dR1, +=) RED_(2, dR2, +=) RED_(3, dR3, +=) }
            if (lane < Kn) {
                if (ww == 0) credL[lane]  = (float)cnt2;
                else         credL[lane] += (float)cnt2;
            }
        }
        __syncthreads();
    }

    // emit partials: i = stat*1216 + c*19 + k  (+ counts as floats)
    float* pb = part + (size_t)blockIdx.x * PARTSZ;
    for (int i = tid; i < 2 * Cn * Kn; i += SBLK) {
        const int stat = i / (Cn * Kn);
        const int rr   = i - stat * (Cn * Kn);
        const int c = rr / Kn, k = rr - c * Kn;
        pb[i] = redf[k * 128 + stat * 64 + c];
    }
    if (tid < Kn) pb[2 * Cn * Kn + tid] = credL[tid];
}

// ---------------- Kernel 2: mean/std + mixing weights -> AB table ----------------
__global__ __launch_bounds__(1024) void k_tables(
    const float* __restrict__ part, const float* __restrict__ aug,
    float* __restrict__ tabAB)
{
    __shared__ float mean_s[Kn * Cn];   // [k*64 + c]
    __shared__ float std_s [Kn * Cn];
    __shared__ float wrow  [Kn * Kn];   // [t*19 + k]
    __shared__ float wsum  [Kn];
    __shared__ float validf[Kn], cntf[Kn];

    const int b = blockIdx.x, tid = threadIdx.x;
    const float* pbase = part + (size_t)b * SCH * PARTSZ;

    if (tid < Kn) {
        float s = 0.f;
        for (int blk = 0; blk < SCH; ++blk)
            s += pbase[(size_t)blk * PARTSZ + 2 * Cn * Kn + tid];
        validf[tid] = (s > 0.f) ? 1.f : 0.f;
        cntf[tid]   = (s > 0.f) ? s : 1.f;
    }
    __syncthreads();

    for (int i = tid; i < Cn * Kn; i += 1024) {             // i = c*19 + k
        float s = 0.f, q = 0.f;
        for (int blk = 0; blk < SCH; ++blk) {
            s += pbase[(size_t)blk * PARTSZ + i];
            q += pbase[(size_t)blk * PARTSZ + Cn * Kn + i];
        }
        const int c = i / Kn, k = i - c * Kn;
        const float cs  = cntf[k];
        const float m   = s / cs;
        const float var = fmaxf(q / cs - m * m, 0.f);
        mean_s[k * Cn + c] = m;
        std_s [k * Cn + c] = sqrtf(var) + EPSF;
    }
    // FIX (R1): Kn*Kn = 361 -> strided loop.
    for (int i = tid; i < Kn * Kn; i += 1024) {
        const int t = i / Kn, k = i - t * Kn;
        wrow[i] = aug[((size_t)b * Kn + t) * Kn + k] * validf[k];
    }
    __syncthreads();
    if (tid < Kn) {
        float s = 0.f;
        for (int k = 0; k < Kn; ++k) s += wrow[tid * Kn + k];
        wsum[tid] = fmaxf(s, EPSF);
    }
    __syncthreads();
    for (int i = tid; i < Kn * Cn; i += 1024) {             // i = t*64 + c
        const int t = i >> 6, c = i & 63;
        const float inv = 1.f / wsum[t];
        float mm = 0.f, ms = 0.f;
        for (int k = 0; k < Kn; ++k) {
            const float wk = wrow[t * Kn + k] * inv;
            mm += wk * mean_s[k * Cn + c];
            ms += wk * std_s [k * Cn + c];
        }
        const float A  = ms / std_s[t * Cn + c];
        const float Bv = mm - mean_s[t * Cn + c] * A;
        const size_t o = ((size_t)b * Cn * Kn + c * Kn + t) * 2;  // [b][c][k][2]
        tabAB[o + 0] = A;
        tabAB[o + 1] = Bv;
    }
}

// ---------------- Kernel 3: out = x*A[gt] + B[gt] ----------------
// R13-verified: 16KB bursts + NT stores -> ~6.9 TB/s combined. Unchanged.
constexpr int ABLK = 1024;
constexpr int ACH  = 64;                   // chunks per image
constexpr int APIX = HWn / ACH;            // 4096 pixels per block

__global__ __launch_bounds__(ABLK, 4) void k_apply(
    const float* __restrict__ x, const int* __restrict__ gt,
    const float* __restrict__ tabAB, float* __restrict__ out)
{
    __shared__ float ABs[Cn * Kn * 2];   // [(c*19 + k)*2 + {A,B}]
    const int tid   = threadIdx.x;
    const int b     = blockIdx.x >> 6;
    const int chunk = blockIdx.x & 63;

    for (int i = tid; i < Cn * Kn * 2; i += ABLK)
        ABs[i] = tabAB[(size_t)b * Cn * Kn * 2 + i];
    __syncthreads();

    const int p0 = chunk * APIX + tid * 4;
    const int4 L = *reinterpret_cast<const int4*>(gt + (size_t)b * HWn + p0);
    const int l0 = min(max(L.x, 0), Kn - 1);
    const int l1 = min(max(L.y, 0), Kn - 1);
    const int l2 = min(max(L.z, 0), Kn - 1);
    const int l3 = min(max(L.w, 0), Kn - 1);

    const float* xp = x   + (size_t)b * Cn * HWn + p0;
    float*       op = out + (size_t)b * Cn * HWn + p0;

    #pragma unroll 4
    for (int c = 0; c < Cn; ++c) {
        const float4 v = *reinterpret_cast<const float4*>(xp + (size_t)c * HWn);
        const int co = c * Kn;
        const float2 ab0 = *reinterpret_cast<const float2*>(&ABs[(co + l0) * 2]);
        const float2 ab1 = *reinterpret_cast<const float2*>(&ABs[(co + l1) * 2]);
        const float2 ab2 = *reinterpret_cast<const float2*>(&ABs[(co + l2) * 2]);
        const float2 ab3 = *reinterpret_cast<const float2*>(&ABs[(co + l3) * 2]);
        float4 o;
        o.x = v.x * ab0.x + ab0.y;
        o.y = v.y * ab1.x + ab1.y;
        o.z = v.z * ab2.x + ab2.y;
        o.w = v.w * ab3.x + ab3.y;
        __builtin_nontemporal_store(__builtin_bit_cast(f32x4_t, o),
                                    reinterpret_cast<f32x4_t*>(op + (size_t)c * HWn));
    }
}

extern "C" void kernel_launch(void* const* d_in, const int* in_sizes, int n_in,
                              void* d_out, int out_size, void* d_ws, size_t ws_size,
                              hipStream_t stream) {
    const float* x   = (const float*)d_in[0];
    const int*   gt  = (const int*)d_in[1];
    const float* aug = (const float*)d_in[2];
    float* out = (float*)d_out;

    float* part  = (float*)d_ws;                                  // 256*2464 = 2.5 MB
    float* tabAB = part + (size_t)Bn * SCH * PARTSZ;              // 4*64*19*2

    k_stats <<<dim3(Bn * SCH), dim3(SBLK), 0, stream>>>(x, gt, part);
    k_tables<<<dim3(Bn),       dim3(1024), 0, stream>>>(part, aug, tabAB);
    k_apply <<<dim3(Bn * ACH), dim3(ABLK), 0, stream>>>(x, gt, tabAB, out);
}

// Round 15
// 174.509 us; speedup vs baseline: 1.0209x; 1.0209x over previous
//
#include <hip/hip_runtime.h>

#define EPSF 1e-7f

constexpr int Bn = 4, Cn = 64, Kn = 19;
constexpr int HWn = 512 * 512;

// k_stats v7 (R15): TLP-overlapped staged MFMA.
// R14 lesson: k_stats is serialization-limited (stage->barrier->compute with
// 1 block/CU; vmcnt(0) drain at each barrier idles HBM during compute).
// Fix: 512-thr blocks, 72KB LDS -> 2 blocks/CU; block A's compute overlaps
// block B's stage. Stat-packed MFMA (R14-verified): B cols 0-15 = x(ch),
// cols 16-31 = x^2(ch) -> one MFMA yields S and Q.
constexpr int SCH   = 128;                 // stats chunks per image
constexpr int SPIX  = HWn / SCH;           // 2048 px per block
constexpr int SBLK  = 512;                 // 8 waves
constexpr int TSTR  = 2056;                // tile row stride (bf16): 4112B -> rows 16B-aligned
constexpr int PARTSZ = 2464;               // 2432 stats + 19 counts + pad

typedef float f32x16_t __attribute__((ext_vector_type(16)));
typedef float f32x4_t  __attribute__((ext_vector_type(4)));
typedef short bf16x8_t __attribute__((ext_vector_type(8)));

#define PKBF(lo, hi) ((__builtin_bit_cast(unsigned, (hi)) & 0xFFFF0000u) | \
                      (__builtin_bit_cast(unsigned, (lo)) >> 16))

__global__ __launch_bounds__(SBLK, 4) void k_stats(
    const float* __restrict__ x, const int* __restrict__ gt,
    float* __restrict__ part)
{
    __shared__ unsigned short tile[16 * TSTR];   // 65,792 B (reused as reduce scratch)
    __shared__ int   lab[SPIX];                  // 8,192 B
    __shared__ float credL[32];                  // total ~74KB -> 2 blocks/CU

    const int tid  = threadIdx.x;
    const int lane = tid & 63;
    const int w    = tid >> 6;                   // wave 0..7
    const int g    = lane >> 5;                  // k-slot half
    const int col  = lane & 31;                  // A row (class) / D col (channel|stat)
    const int ch16 = col & 15;                   // B channel row within tile

    const int b    = blockIdx.x >> 7;
    const int pix0 = (blockIdx.x & 127) * SPIX;
    const float* xb  = x  + (size_t)b * Cn * HWn + pix0;
    const int*   gtb = gt + (size_t)b * HWn + pix0;

    // stage labels once (clamped): 512 thr x int4 = 2048
    {
        const int4 v = *reinterpret_cast<const int4*>(gtb + tid * 4);
        int4 cl;
        cl.x = min(max(v.x, 0), Kn - 1); cl.y = min(max(v.y, 0), Kn - 1);
        cl.z = min(max(v.z, 0), Kn - 1); cl.w = min(max(v.w, 0), Kn - 1);
        *reinterpret_cast<int4*>(&lab[tid * 4]) = cl;
    }

    // 4 named round accumulators (rule #20: no runtime-indexed arrays)
    f32x16_t dR0 = (f32x16_t)0.f, dR1 = (f32x16_t)0.f;
    f32x16_t dR2 = (f32x16_t)0.f, dR3 = (f32x16_t)0.f;
    int cnt = 0;

    // stage round R: wave w loads channels R*16 + {2w, 2w+1}, 8KB/row contiguous
#define STAGE_(R) { \
    _Pragma("unroll") \
    for (int cc = 0; cc < 2; ++cc) { \
        const float* src = xb + (size_t)((R) * 16 + w * 2 + cc) * HWn; \
        unsigned short* dst = &tile[(w * 2 + cc) * TSTR]; \
        _Pragma("unroll") \
        for (int i = 0; i < 8; ++i) { \
            const float4 v = *reinterpret_cast<const float4*>(src + i * 256 + lane * 4); \
            uint2 pk; pk.x = PKBF(v.x, v.y); pk.y = PKBF(v.z, v.w); \
            *reinterpret_cast<uint2*>(&dst[i * 256 + lane * 4]) = pk; \
        } \
    } }

    // compute round R: wave w owns pixels [w*256, w*256+256), 16 MFMA steps.
    // B: cols<16 feed x, cols>=16 feed x^2 of channel ch16 (one MFMA -> S+Q).
    // A onehot / k-slot convention unchanged (R11/R14-verified); C/D layout:
    // col=lane&31, row=(reg&3)+8*(reg>>2)+4*(lane>>5).
#define COMPUTE_(R, D, CNTON) { \
    _Pragma("unroll 1") \
    for (int s = 0; s < 16; ++s) { \
        const int pg = w * 256 + s * 16 + 8 * g; \
        uint4 bw = *reinterpret_cast<const uint4*>(&tile[ch16 * TSTR + pg]); \
        if (col >= 16) { \
            const float f0 = __builtin_bit_cast(float, bw.x << 16); \
            const float f1 = __builtin_bit_cast(float, bw.x & 0xFFFF0000u); \
            const float f2 = __builtin_bit_cast(float, bw.y << 16); \
            const float f3 = __builtin_bit_cast(float, bw.y & 0xFFFF0000u); \
            const float f4 = __builtin_bit_cast(float, bw.z << 16); \
            const float f5 = __builtin_bit_cast(float, bw.z & 0xFFFF0000u); \
            const float f6 = __builtin_bit_cast(float, bw.w << 16); \
            const float f7 = __builtin_bit_cast(float, bw.w & 0xFFFF0000u); \
            bw.x = PKBF(f0 * f0, f1 * f1); bw.y = PKBF(f2 * f2, f3 * f3); \
            bw.z = PKBF(f4 * f4, f5 * f5); bw.w = PKBF(f6 * f6, f7 * f7); \
        } \
        const int4 L0 = *reinterpret_cast<const int4*>(&lab[pg]); \
        const int4 L1 = *reinterpret_cast<const int4*>(&lab[pg + 4]); \
        const bool e0 = (L0.x == col), e1 = (L0.y == col); \
        const bool e2 = (L0.z == col), e3 = (L0.w == col); \
        const bool e4 = (L1.x == col), e5 = (L1.y == col); \
        const bool e6 = (L1.z == col), e7 = (L1.w == col); \
        int4 av; \
        av.x = (e0 ? 0x3F80u : 0u) | (e1 ? 0x3F800000u : 0u); \
        av.y = (e2 ? 0x3F80u : 0u) | (e3 ? 0x3F800000u : 0u); \
        av.z = (e4 ? 0x3F80u : 0u) | (e5 ? 0x3F800000u : 0u); \
        av.w = (e6 ? 0x3F80u : 0u) | (e7 ? 0x3F800000u : 0u); \
        if (CNTON) cnt += (int)e0 + (int)e1 + (int)e2 + (int)e3 \
                        + (int)e4 + (int)e5 + (int)e6 + (int)e7; \
        D = __builtin_amdgcn_mfma_f32_32x32x16_bf16( \
                __builtin_bit_cast(bf16x8_t, av), \
                __builtin_bit_cast(bf16x8_t, bw), D, 0, 0, 0); \
    } }

    __syncthreads();                 // labels staged
    STAGE_(0)
    __syncthreads();
    COMPUTE_(0, dR0, true)           // counts once: every round covers same 2048 px
    __syncthreads();
    STAGE_(1)
    __syncthreads();
    COMPUTE_(1, dR1, false)
    __syncthreads();
    STAGE_(2)
    __syncthreads();
    COMPUTE_(2, dR2, false)
    __syncthreads();
    STAGE_(3)
    __syncthreads();
    COMPUTE_(3, dR3, false)

    const int cnt2 = cnt + __shfl(cnt, col + 32, 64);

    // cross-wave reduce into tile-as-scratch: redf[k*128 + stat*64 + ch]
    __syncthreads();
    float* redf = reinterpret_cast<float*>(tile);
    const int statO = (col >> 4) * 64;           // 0 = S, 64 = Q
#define RED_(R, D, OP) { \
    _Pragma("unroll") \
    for (int r = 0; r < 16; ++r) { \
        const int krow = (r & 3) + 8 * (r >> 2) + 4 * g; \
        if (krow < Kn) redf[krow * 128 + statO + (R) * 16 + ch16] OP D[r]; \
    } }
    #pragma unroll 1
    for (int ww = 0; ww < 8; ++ww) {
        if (w == ww) {
            if (ww == 0) { RED_(0, dR0, =)  RED_(1, dR1, =)  RED_(2, dR2, =)  RED_(3, dR3, =) }
            else         { RED_(0, dR0, +=) RED_(1, dR1, +=) RED_(2, dR2, +=) RED_(3, dR3, +=) }
            if (lane < Kn) {
                if (ww == 0) credL[lane]  = (float)cnt2;
                else         credL[lane] += (float)cnt2;
            }
        }
        __syncthreads();
    }

    // emit partials: i = stat*1216 + c*19 + k  (+ counts as floats)
    float* pb = part + (size_t)blockIdx.x * PARTSZ;
    for (int i = tid; i < 2 * Cn * Kn; i += SBLK) {
        const int stat = i / (Cn * Kn);
        const int rr   = i - stat * (Cn * Kn);
        const int c = rr / Kn, k = rr - c * Kn;
        pb[i] = redf[k * 128 + stat * 64 + c];
    }
    if (tid < Kn) pb[2 * Cn * Kn + tid] = credL[tid];
}

// ---------------- Kernel 2: mean/std + mixing weights -> AB table ----------------
__global__ __launch_bounds__(1024) void k_tables(
    const float* __restrict__ part, const float* __restrict__ aug,
    float* __restrict__ tabAB)
{
    __shared__ float mean_s[Kn * Cn];   // [k*64 + c]
    __shared__ float std_s [Kn * Cn];
    __shared__ float wrow  [Kn * Kn];   // [t*19 + k]
    __shared__ float wsum  [Kn];
    __shared__ float validf[Kn], cntf[Kn];

    const int b = blockIdx.x, tid = threadIdx.x;
    const float* pbase = part + (size_t)b * SCH * PARTSZ;

    if (tid < Kn) {
        float s = 0.f;
        for (int blk = 0; blk < SCH; ++blk)
            s += pbase[(size_t)blk * PARTSZ + 2 * Cn * Kn + tid];
        validf[tid] = (s > 0.f) ? 1.f : 0.f;
        cntf[tid]   = (s > 0.f) ? s : 1.f;
    }
    __syncthreads();

    for (int i = tid; i < Cn * Kn; i += 1024) {             // i = c*19 + k
        float s = 0.f, q = 0.f;
        for (int blk = 0; blk < SCH; ++blk) {
            s += pbase[(size_t)blk * PARTSZ + i];
            q += pbase[(size_t)blk * PARTSZ + Cn * Kn + i];
        }
        const int c = i / Kn, k = i - c * Kn;
        const float cs  = cntf[k];
        const float m   = s / cs;
        const float var = fmaxf(q / cs - m * m, 0.f);
        mean_s[k * Cn + c] = m;
        std_s [k * Cn + c] = sqrtf(var) + EPSF;
    }
    // FIX (R1): Kn*Kn = 361 -> strided loop.
    for (int i = tid; i < Kn * Kn; i += 1024) {
        const int t = i / Kn, k = i - t * Kn;
        wrow[i] = aug[((size_t)b * Kn + t) * Kn + k] * validf[k];
    }
    __syncthreads();
    if (tid < Kn) {
        float s = 0.f;
        for (int k = 0; k < Kn; ++k) s += wrow[tid * Kn + k];
        wsum[tid] = fmaxf(s, EPSF);
    }
    __syncthreads();
    for (int i = tid; i < Kn * Cn; i += 1024) {             // i = t*64 + c
        const int t = i >> 6, c = i & 63;
        const float inv = 1.f / wsum[t];
        float mm = 0.f, ms = 0.f;
        for (int k = 0; k < Kn; ++k) {
            const float wk = wrow[t * Kn + k] * inv;
            mm += wk * mean_s[k * Cn + c];
            ms += wk * std_s [k * Cn + c];
        }
        const float A  = ms / std_s[t * Cn + c];
        const float Bv = mm - mean_s[t * Cn + c] * A;
        const size_t o = ((size_t)b * Cn * Kn + c * Kn + t) * 2;  // [b][c][k][2]
        tabAB[o + 0] = A;
        tabAB[o + 1] = Bv;
    }
}

// ---------------- Kernel 3: out = x*A[gt] + B[gt] ----------------
// R13-verified: 16KB bursts + NT stores -> ~6.9 TB/s combined. Unchanged.
constexpr int ABLK = 1024;
constexpr int ACH  = 64;                   // chunks per image
constexpr int APIX = HWn / ACH;            // 4096 pixels per block

__global__ __launch_bounds__(ABLK, 4) void k_apply(
    const float* __restrict__ x, const int* __restrict__ gt,
    const float* __restrict__ tabAB, float* __restrict__ out)
{
    __shared__ float ABs[Cn * Kn * 2];   // [(c*19 + k)*2 + {A,B}]
    const int tid   = threadIdx.x;
    const int b     = blockIdx.x >> 6;
    const int chunk = blockIdx.x & 63;

    for (int i = tid; i < Cn * Kn * 2; i += ABLK)
        ABs[i] = tabAB[(size_t)b * Cn * Kn * 2 + i];
    __syncthreads();

    const int p0 = chunk * APIX + tid * 4;
    const int4 L = *reinterpret_cast<const int4*>(gt + (size_t)b * HWn + p0);
    const int l0 = min(max(L.x, 0), Kn - 1);
    const int l1 = min(max(L.y, 0), Kn - 1);
    const int l2 = min(max(L.z, 0), Kn - 1);
    const int l3 = min(max(L.w, 0), Kn - 1);

    const float* xp = x   + (size_t)b * Cn * HWn + p0;
    float*       op = out + (size_t)b * Cn * HWn + p0;

    #pragma unroll 4
    for (int c = 0; c < Cn; ++c) {
        const float4 v = *reinterpret_cast<const float4*>(xp + (size_t)c * HWn);
        const int co = c * Kn;
        const float2 ab0 = *reinterpret_cast<const float2*>(&ABs[(co + l0) * 2]);
        const float2 ab1 = *reinterpret_cast<const float2*>(&ABs[(co + l1) * 2]);
        const float2 ab2 = *reinterpret_cast<const float2*>(&ABs[(co + l2) * 2]);
        const float2 ab3 = *reinterpret_cast<const float2*>(&ABs[(co + l3) * 2]);
        float4 o;
        o.x = v.x * ab0.x + ab0.y;
        o.y = v.y * ab1.x + ab1.y;
        o.z = v.z * ab2.x + ab2.y;
        o.w = v.w * ab3.x + ab3.y;
        __builtin_nontemporal_store(__builtin_bit_cast(f32x4_t, o),
                                    reinterpret_cast<f32x4_t*>(op + (size_t)c * HWn));
    }
}

extern "C" void kernel_launch(void* const* d_in, const int* in_sizes, int n_in,
                              void* d_out, int out_size, void* d_ws, size_t ws_size,
                              hipStream_t stream) {
    const float* x   = (const float*)d_in[0];
    const int*   gt  = (const int*)d_in[1];
    const float* aug = (const float*)d_in[2];
    float* out = (float*)d_out;

    float* part  = (float*)d_ws;                                  // 512*2464 = 5 MB
    float* tabAB = part + (size_t)Bn * SCH * PARTSZ;              // 4*64*19*2

    k_stats <<<dim3(Bn * SCH), dim3(SBLK), 0, stream>>>(x, gt, part);
    k_tables<<<dim3(Bn),       dim3(1024), 0, stream>>>(part, aug, tabAB);
    k_apply <<<dim3(Bn * ACH), dim3(ABLK), 0, stream>>>(x, gt, tabAB, out);
}

// Round 16
// 174.483 us; speedup vs baseline: 1.0210x; 1.0002x over previous
//
#include <hip/hip_runtime.h>

#define EPSF 1e-7f

constexpr int Bn = 4, Cn = 64, Kn = 19;
constexpr int HWn = 512 * 512;

// k_stats v8 (R16): async-DMA staged MFMA.
// R15 lesson: staging was VGPR-starved on MLP (64 acc VGPRs leave ~10 loads in
// flight -> 2.5KB/CU << 9KB Little's-law need -> ~3 TB/s latency-bound; both
// burst-length (R14) and TLP (R15) changes were null because neither added
// in-flight bytes). Fix: global_load_lds (16B) -> zero VGPR per in-flight
// load, 128KB/CU in flight. Tile is linear f32 (DMA can't pack); bf16 pack +
// squaring move to compute. 8 rounds = 4 ch-groups x 2 px-halves; px-halves
// k-accumulate into the same named acc (rule #20 safe).
constexpr int SCH   = 128;                 // stats chunks per image
constexpr int SPIX  = HWn / SCH;           // 2048 px per block
constexpr int SBLK  = 512;                 // 8 waves
constexpr int TSTR4 = 1028;                // f32 tile row stride (4 mod 32 -> spread banks)
constexpr int PARTSZ = 2464;               // 2432 stats + 19 counts + pad

typedef float f32x16_t __attribute__((ext_vector_type(16)));
typedef float f32x4_t  __attribute__((ext_vector_type(4)));
typedef short bf16x8_t __attribute__((ext_vector_type(8)));

#define PKBF(lo, hi) ((__builtin_bit_cast(unsigned, (hi)) & 0xFFFF0000u) | \
                      (__builtin_bit_cast(unsigned, (lo)) >> 16))

typedef const __attribute__((address_space(1))) void gas_void;
typedef __attribute__((address_space(3))) void las_void;

__device__ __forceinline__ void gload16(const float* g, float* l) {
    // literal size=16 (must be ICE); dest = wave-uniform base + lane*16,
    // src = per-lane address (guide m97/m104 semantics).
    __builtin_amdgcn_global_load_lds((gas_void*)g, (las_void*)l, 16, 0, 0);
}

__global__ __launch_bounds__(SBLK, 4) void k_stats(
    const float* __restrict__ x, const int* __restrict__ gt,
    float* __restrict__ part)
{
    __shared__ float tile[16 * TSTR4];           // 65,792 B (reused as reduce scratch)
    __shared__ int   lab[SPIX];                  // 8,192 B
    __shared__ float credL[32];                  // total ~74KB -> 2 blocks/CU

    const int tid  = threadIdx.x;
    const int lane = tid & 63;
    const int w    = tid >> 6;                   // wave 0..7
    const int g    = lane >> 5;                  // k-slot half
    const int col  = lane & 31;                  // A row (class) / D col (channel|stat)
    const int ch16 = col & 15;                   // B channel row within tile

    const int b    = blockIdx.x >> 7;
    const int pix0 = (blockIdx.x & 127) * SPIX;
    const float* xb  = x  + (size_t)b * Cn * HWn + pix0;
    const int*   gtb = gt + (size_t)b * HWn + pix0;

    // stage labels once (clamped): 512 thr x int4 = 2048
    {
        const int4 v = *reinterpret_cast<const int4*>(gtb + tid * 4);
        int4 cl;
        cl.x = min(max(v.x, 0), Kn - 1); cl.y = min(max(v.y, 0), Kn - 1);
        cl.z = min(max(v.z, 0), Kn - 1); cl.w = min(max(v.w, 0), Kn - 1);
        *reinterpret_cast<int4*>(&lab[tid * 4]) = cl;
    }

    // 4 named ch-group accumulators (rule #20)
    f32x16_t dG0 = (f32x16_t)0.f, dG1 = (f32x16_t)0.f;
    f32x16_t dG2 = (f32x16_t)0.f, dG3 = (f32x16_t)0.f;
    int cnt = 0;

    // stage round (CG, PH): wave w DMAs channels CG*16+{2w,2w+1}, px half PH.
    // 8 x global_load_lds per wave, no VGPR round-trip, all in flight at once.
#define STAGE_(CG, PH) { \
    _Pragma("unroll") \
    for (int cc = 0; cc < 2; ++cc) { \
        const int row = w * 2 + cc; \
        const float* src = xb + (size_t)((CG) * 16 + row) * HWn + (PH) * 1024 + lane * 4; \
        float* dst = &tile[row * TSTR4]; \
        _Pragma("unroll") \
        for (int seg = 0; seg < 4; ++seg) \
            gload16(src + seg * 256, dst + seg * 256); \
    } }

    // compute round: wave w owns px [w*128, w*128+128) of half PH, 8 MFMA steps.
    // B: cols<16 = x(ch16), cols>=16 = x^2(ch16) (R14-verified stat-packing).
    // A onehot / k-slot convention and C/D layout unchanged (R11-verified):
    // col=lane&31, row=(reg&3)+8*(reg>>2)+4*(lane>>5).
#define COMPUTE_(PH, D, CNTON) { \
    _Pragma("unroll 1") \
    for (int s = 0; s < 8; ++s) { \
        const int pg = w * 128 + s * 16 + 8 * g; \
        const float4 va = *reinterpret_cast<const float4*>(&tile[ch16 * TSTR4 + pg]); \
        const float4 vb = *reinterpret_cast<const float4*>(&tile[ch16 * TSTR4 + pg + 4]); \
        float v0 = va.x, v1 = va.y, v2 = va.z, v3 = va.w; \
        float v4 = vb.x, v5 = vb.y, v6 = vb.z, v7 = vb.w; \
        if (col >= 16) { v0 *= v0; v1 *= v1; v2 *= v2; v3 *= v3; \
                         v4 *= v4; v5 *= v5; v6 *= v6; v7 *= v7; } \
        uint4 bw; \
        bw.x = PKBF(v0, v1); bw.y = PKBF(v2, v3); \
        bw.z = PKBF(v4, v5); bw.w = PKBF(v6, v7); \
        const int4 L0 = *reinterpret_cast<const int4*>(&lab[(PH) * 1024 + pg]); \
        const int4 L1 = *reinterpret_cast<const int4*>(&lab[(PH) * 1024 + pg + 4]); \
        const bool e0 = (L0.x == col), e1 = (L0.y == col); \
        const bool e2 = (L0.z == col), e3 = (L0.w == col); \
        const bool e4 = (L1.x == col), e5 = (L1.y == col); \
        const bool e6 = (L1.z == col), e7 = (L1.w == col); \
        int4 av; \
        av.x = (e0 ? 0x3F80u : 0u) | (e1 ? 0x3F800000u : 0u); \
        av.y = (e2 ? 0x3F80u : 0u) | (e3 ? 0x3F800000u : 0u); \
        av.z = (e4 ? 0x3F80u : 0u) | (e5 ? 0x3F800000u : 0u); \
        av.w = (e6 ? 0x3F80u : 0u) | (e7 ? 0x3F800000u : 0u); \
        if (CNTON) cnt += (int)e0 + (int)e1 + (int)e2 + (int)e3 \
                        + (int)e4 + (int)e5 + (int)e6 + (int)e7; \
        D = __builtin_amdgcn_mfma_f32_32x32x16_bf16( \
                __builtin_bit_cast(bf16x8_t, av), \
                __builtin_bit_cast(bf16x8_t, bw), D, 0, 0, 0); \
    } }

    // barrier after STAGE drains vmcnt(0) (incl. LDS-DMA) -> tile ready;
    // barrier after COMPUTE -> tile free for next round's DMA.
#define ROUND_(CG, PH, D, CNTON) \
    STAGE_(CG, PH) \
    __syncthreads(); \
    COMPUTE_(PH, D, CNTON) \
    __syncthreads();

    ROUND_(0, 0, dG0, true)          // count each pixel once (cg==0 rounds)
    ROUND_(1, 0, dG1, false)
    ROUND_(2, 0, dG2, false)
    ROUND_(3, 0, dG3, false)
    ROUND_(0, 1, dG0, true)
    ROUND_(1, 1, dG1, false)
    ROUND_(2, 1, dG2, false)
    ROUND_(3, 1, dG3, false)

    const int cnt2 = cnt + __shfl(cnt, col + 32, 64);

    // cross-wave reduce into tile-as-scratch: redf[k*128 + stat*64 + ch]
    float* redf = tile;
    const int statO = (col >> 4) * 64;           // 0 = S, 64 = Q
#define RED_(R, D, OP) { \
    _Pragma("unroll") \
    for (int r = 0; r < 16; ++r) { \
        const int krow = (r & 3) + 8 * (r >> 2) + 4 * g; \
        if (krow < Kn) redf[krow * 128 + statO + (R) * 16 + ch16] OP D[r]; \
    } }
    #pragma unroll 1
    for (int ww = 0; ww < 8; ++ww) {
        if (w == ww) {
            if (ww == 0) { RED_(0, dG0, =)  RED_(1, dG1, =)  RED_(2, dG2, =)  RED_(3, dG3, =) }
            else         { RED_(0, dG0, +=) RED_(1, dG1, +=) RED_(2, dG2, +=) RED_(3, dG3, +=) }
            if (lane < Kn) {
                if (ww == 0) credL[lane]  = (float)cnt2;
                else         credL[lane] += (float)cnt2;
            }
        }
        __syncthreads();
    }

    // emit partials: i = stat*1216 + c*19 + k  (+ counts as floats)
    float* pb = part + (size_t)blockIdx.x * PARTSZ;
    for (int i = tid; i < 2 * Cn * Kn; i += SBLK) {
        const int stat = i / (Cn * Kn);
        const int rr   = i - stat * (Cn * Kn);
        const int c = rr / Kn, k = rr - c * Kn;
        pb[i] = redf[k * 128 + stat * 64 + c];
    }
    if (tid < Kn) pb[2 * Cn * Kn + tid] = credL[tid];
}

// ---------------- Kernel 2: mean/std + mixing weights -> AB table ----------------
__global__ __launch_bounds__(1024) void k_tables(
    const float* __restrict__ part, const float* __restrict__ aug,
    float* __restrict__ tabAB)
{
    __shared__ float mean_s[Kn * Cn];   // [k*64 + c]
    __shared__ float std_s [Kn * Cn];
    __shared__ float wrow  [Kn * Kn];   // [t*19 + k]
    __shared__ float wsum  [Kn];
    __shared__ float validf[Kn], cntf[Kn];

    const int b = blockIdx.x, tid = threadIdx.x;
    const float* pbase = part + (size_t)b * SCH * PARTSZ;

    if (tid < Kn) {
        float s = 0.f;
        for (int blk = 0; blk < SCH; ++blk)
            s += pbase[(size_t)blk * PARTSZ + 2 * Cn * Kn + tid];
        validf[tid] = (s > 0.f) ? 1.f : 0.f;
        cntf[tid]   = (s > 0.f) ? s : 1.f;
    }
    __syncthreads();

    for (int i = tid; i < Cn * Kn; i += 1024) {             // i = c*19 + k
        float s = 0.f, q = 0.f;
        for (int blk = 0; blk < SCH; ++blk) {
            s += pbase[(size_t)blk * PARTSZ + i];
            q += pbase[(size_t)blk * PARTSZ + Cn * Kn + i];
        }
        const int c = i / Kn, k = i - c * Kn;
        const float cs  = cntf[k];
        const float m   = s / cs;
        const float var = fmaxf(q / cs - m * m, 0.f);
        mean_s[k * Cn + c] = m;
        std_s [k * Cn + c] = sqrtf(var) + EPSF;
    }
    // FIX (R1): Kn*Kn = 361 -> strided loop.
    for (int i = tid; i < Kn * Kn; i += 1024) {
        const int t = i / Kn, k = i - t * Kn;
        wrow[i] = aug[((size_t)b * Kn + t) * Kn + k] * validf[k];
    }
    __syncthreads();
    if (tid < Kn) {
        float s = 0.f;
        for (int k = 0; k < Kn; ++k) s += wrow[tid * Kn + k];
        wsum[tid] = fmaxf(s, EPSF);
    }
    __syncthreads();
    for (int i = tid; i < Kn * Cn; i += 1024) {             // i = t*64 + c
        const int t = i >> 6, c = i & 63;
        const float inv = 1.f / wsum[t];
        float mm = 0.f, ms = 0.f;
        for (int k = 0; k < Kn; ++k) {
            const float wk = wrow[t * Kn + k] * inv;
            mm += wk * mean_s[k * Cn + c];
            ms += wk * std_s [k * Cn + c];
        }
        const float A  = ms / std_s[t * Cn + c];
        const float Bv = mm - mean_s[t * Cn + c] * A;
        const size_t o = ((size_t)b * Cn * Kn + c * Kn + t) * 2;  // [b][c][k][2]
        tabAB[o + 0] = A;
        tabAB[o + 1] = Bv;
    }
}

// ---------------- Kernel 3: out = x*A[gt] + B[gt] ----------------
// R13-verified: 16KB bursts + NT stores -> ~6.9 TB/s combined. Unchanged.
constexpr int ABLK = 1024;
constexpr int ACH  = 64;                   // chunks per image
constexpr int APIX = HWn / ACH;            // 4096 pixels per block

__global__ __launch_bounds__(ABLK, 4) void k_apply(
    const float* __restrict__ x, const int* __restrict__ gt,
    const float* __restrict__ tabAB, float* __restrict__ out)
{
    __shared__ float ABs[Cn * Kn * 2];   // [(c*19 + k)*2 + {A,B}]
    const int tid   = threadIdx.x;
    const int b     = blockIdx.x >> 6;
    const int chunk = blockIdx.x & 63;

    for (int i = tid; i < Cn * Kn * 2; i += ABLK)
        ABs[i] = tabAB[(size_t)b * Cn * Kn * 2 + i];
    __syncthreads();

    const int p0 = chunk * APIX + tid * 4;
    const int4 L = *reinterpret_cast<const int4*>(gt + (size_t)b * HWn + p0);
    const int l0 = min(max(L.x, 0), Kn - 1);
    const int l1 = min(max(L.y, 0), Kn - 1);
    const int l2 = min(max(L.z, 0), Kn - 1);
    const int l3 = min(max(L.w, 0), Kn - 1);

    const float* xp = x   + (size_t)b * Cn * HWn + p0;
    float*       op = out + (size_t)b * Cn * HWn + p0;

    #pragma unroll 4
    for (int c = 0; c < Cn; ++c) {
        const float4 v = *reinterpret_cast<const float4*>(xp + (size_t)c * HWn);
        const int co = c * Kn;
        const float2 ab0 = *reinterpret_cast<const float2*>(&ABs[(co + l0) * 2]);
        const float2 ab1 = *reinterpret_cast<const float2*>(&ABs[(co + l1) * 2]);
        const float2 ab2 = *reinterpret_cast<const float2*>(&ABs[(co + l2) * 2]);
        const float2 ab3 = *reinterpret_cast<const float2*>(&ABs[(co + l3) * 2]);
        float4 o;
        o.x = v.x * ab0.x + ab0.y;
        o.y = v.y * ab1.x + ab1.y;
        o.z = v.z * ab2.x + ab2.y;
        o.w = v.w * ab3.x + ab3.y;
        __builtin_nontemporal_store(__builtin_bit_cast(f32x4_t, o),
                                    reinterpret_cast<f32x4_t*>(op + (size_t)c * HWn));
    }
}

extern "C" void kernel_launch(void* const* d_in, const int* in_sizes, int n_in,
                              void* d_out, int out_size, void* d_ws, size_t ws_size,
                              hipStream_t stream) {
    const float* x   = (const float*)d_in[0];
    const int*   gt  = (const int*)d_in[1];
    const float* aug = (const float*)d_in[2];
    float* out = (float*)d_out;

    float* part  = (float*)d_ws;                                  // 512*2464 = 5 MB
    float* tabAB = part + (size_t)Bn * SCH * PARTSZ;              // 4*64*19*2

    k_stats <<<dim3(Bn * SCH), dim3(SBLK), 0, stream>>>(x, gt, part);
    k_tables<<<dim3(Bn),       dim3(1024), 0, stream>>>(part, aug, tabAB);
    k_apply <<<dim3(Bn * ACH), dim3(ABLK), 0, stream>>>(x, gt, tabAB, out);
}